// Round 14
// baseline (1540.380 us; speedup 1.0000x reference)
//
#include <hip/hip_runtime.h>

typedef int      i32x4 __attribute__((ext_vector_type(4)));
typedef float    f32x4 __attribute__((ext_vector_type(4)));
typedef unsigned u32x2 __attribute__((ext_vector_type(2)));

#define RNN_H 128
#define RNN_T 2048
#define RNN_B 8192
#define RNN_C 10
#define BLK_N 32                // two 16-col tiles per block: A = even waves, B = odd
#define QSW 32512.0f            // 127*256: fixed-point scale for W and h
#define K2E 2.885390081777927f  // 2*log2(e), folded into kk/wx/bh

// LDS-only barrier: drain ds ops, never vmcnt (x prefetch stays in flight).
#define BAR() asm volatile("s_waitcnt lgkmcnt(0)\n\ts_barrier" ::: "memory")
#define MEMPIN() asm volatile("" ::: "memory")

__device__ __forceinline__ i32x4 mfma_i8(i32x4 a, i32x4 b, i32x4 c) {
  return __builtin_amdgcn_mfma_i32_16x16x64_i8(a, b, c, 0, 0, 0);
}

// k-bijection for 16x16x64 i8 frags (byte p of the 4-dword operand, lane
// group g = lane>>4): k = 64*slot + 4g + (p&3) + 16*jg(p>>2). Per-wave jg
// permutation puts the own-half j-groups at frag dwords 0,1 (A-fill permuted
// identically, so sum over k is unchanged) -> register recycle, no muxes.
// h = q/32512, q = 256a + b; W row-scaled 15-bit -> (wa, wb) int8 pairs.
// X = 256*P1 + P23, P1 = S wa*a, P23 = S(wa*b + wb*a) (wb*b dropped ~2e-5).
//
// Role-split schedule (tests paired wave->SIMD mapping wv>>1):
//  interval 1: even waves (tile A): 12 MFMAs over h_A(t).
//              odd  waves (tile B): epi -> h_B(t+1), LDS write.   BAR.
//  interval 2: even waves: epi -> h_A(t+1), write.
//              odd  waves: 12 MFMAs over h_B(t+1).                BAR.
// If SIMDs host one even + one odd wave, matrix and VALU pipes are both fed
// every interval -- deterministic cross-wave overlap, no scheduler luck.

__global__ __launch_bounds__(512, 2)
void rnn_fused(const float* __restrict__ x, const float* __restrict__ w_hx,
               const float* __restrict__ w_hh, const float* __restrict__ b_h,
               const float* __restrict__ w_ph, const float* __restrict__ b_p,
               float* __restrict__ out)
{
  // single-buffered h per tile: [tile][slot(2)][part a/b][half(2)][lane] = 8 KiB
  __shared__ u32x2 hbuf[2][2][2][2][64];
  __shared__ float rs[128];   // per-row W scales (shared by both tiles)

  const int tid  = threadIdx.x;
  const int lane = tid & 63;
  const int wv   = tid >> 6;       // 0..7
  const int grp  = wv & 1;         // 0 = tile A, 1 = tile B
  const int w4   = wv >> 1;        // 0..3: rows [32*w4, 32*w4+32) of own tile
  const int g    = lane >> 4;
  const int l15  = lane & 15;
  const int n0   = blockIdx.x * BLK_N;
  const int sw = w4 >> 1, hw = w4 & 1, so = sw ^ 1;

  { // zero h(0) for both tiles (1024 u32x2 entries, 512 threads)
    u32x2 z = {0u, 0u};
    u32x2* p = &hbuf[0][0][0][0][0];
    p[tid] = z; p[tid + 512] = z;
  }

  // ---- W quantization: per-row 15-bit fixed point, split to int8 (wa, wb).
  // li = 0: own slot with per-wave jg permutation; li = 1: other slot natural.
  i32x4 WA[2][2], WB[2][2];
  float rm[2];
  #pragma unroll
  for (int mt = 0; mt < 2; ++mt) {
    const float* wrow = w_hh + (size_t)(w4*32 + mt*16 + l15)*RNN_H + 4*g;
    float vals[2][4][4];
    float mx = 0.0f;
    #pragma unroll
    for (int li = 0; li < 2; ++li) {
      const int s = li ? so : sw;
      #pragma unroll
      for (int d = 0; d < 4; ++d) {
        const int jg = li ? d : ((d < 2) ? (2*hw + d) : (2*(hw^1) + (d-2)));
        f32x4 v = *(const f32x4*)(wrow + s*64 + jg*16);
        #pragma unroll
        for (int r = 0; r < 4; ++r) { vals[li][d][r] = v[r]; mx = fmaxf(mx, fabsf(v[r])); }
      }
    }
    mx = fmaxf(mx, __shfl_xor(mx, 16));   // combine the 4 g-lanes of this row
    mx = fmaxf(mx, __shfl_xor(mx, 32));
    const float inv = (mx > 0.0f) ? (QSW / mx) : 0.0f;
    rm[mt] = mx * (1.0f / QSW);
    #pragma unroll
    for (int li = 0; li < 2; ++li)
      #pragma unroll
      for (int d = 0; d < 4; ++d) {
        unsigned pa = 0, pb = 0;
        #pragma unroll
        for (int r = 0; r < 4; ++r) {
          const int Wq  = (int)rintf(vals[li][d][r] * inv);  // |Wq| <= 32512
          const int wa  = (Wq + 128) >> 8;                   // [-127, 127]
          const int wbv = Wq - (wa << 8);                    // [-128, 127]
          pa |= ((unsigned)(wa  & 255)) << (8*r);
          pb |= ((unsigned)(wbv & 255)) << (8*r);
        }
        WA[mt][li][d] = (int)pa;
        WB[mt][li][d] = (int)pb;
      }
  }

  if (g == 0 && grp == 0) {           // publish row scales (rows 32w4+16mt+l15)
    rs[w4*32 +  0 + l15] = rm[0];
    rs[w4*32 + 16 + l15] = rm[1];
  }
  __syncthreads();

  // per-C/D-reg constants (K2E folded): m = 32w4 + 16mt + 4g + r
  f32x4 kk2[2], wx2[2], bh2[2];
  #pragma unroll
  for (int mt = 0; mt < 2; ++mt)
    #pragma unroll
    for (int r = 0; r < 4; ++r) {
      const int m = w4*32 + mt*16 + 4*g + r;
      kk2[mt][r] = rs[m] * (K2E / 127.0f);
      wx2[mt][r] = w_hx[m] * K2E;
      bh2[mt][r] = b_h[m] * K2E;
    }

  // x stream for this wave's tile column
  const float* px = x + (size_t)(n0 + grp*16 + l15) * RNN_T;
  f32x4 xc = *(const f32x4*)px;

  const i32x4 ZI = {0,0,0,0};
  u32x2 ownA = {0u,0u}, ownB = {0u,0u};   // own half frags (h(0) = 0)
  i32x4 P1[2], P23[2];                    // B primed: first epi gives h_B(1)
  P1[0] = ZI; P1[1] = ZI; P23[0] = ZI; P23[1] = ZI;

  // epilogue constants (VGPR-resident; v_perm/v_pk_add take no literals)
  const unsigned c0080 = 0x00800080u;   // +128 per i16 (a-byte rounding)
  const unsigned selA  = 0x07050301u;   // a-bytes: bytes 1,3 of each i16 pair
  const unsigned selB  = 0x06040200u;   // b-bytes: bytes 0,2
  const float TPP = 32512.0f / 32767.0f;  // pknorm prescale -> q = rint(t*32512)
  const float TPN = -2.0f * TPP;

  __syncthreads();

  // MFMA role: 6 x ds_read_b64 from own tile + 12 i8 MFMAs -> P1/P23.
  auto do_mfma = [&]() {
    const u32x2 poA = hbuf[grp][sw][0][hw^1][lane];   // own slot, partner half
    const u32x2 poB = hbuf[grp][sw][1][hw^1][lane];
    const u32x2 oa0 = hbuf[grp][so][0][0][lane];      // other slot, both halves
    const u32x2 oa1 = hbuf[grp][so][0][1][lane];
    const u32x2 ob0 = hbuf[grp][so][1][0][lane];
    const u32x2 ob1 = hbuf[grp][so][1][1][lane];
    MEMPIN();
    const i32x4 FaOwn = {(int)ownA[0], (int)ownA[1], (int)poA[0], (int)poA[1]};
    const i32x4 FbOwn = {(int)ownB[0], (int)ownB[1], (int)poB[0], (int)poB[1]};
    const i32x4 FaOth = {(int)oa0[0], (int)oa0[1], (int)oa1[0], (int)oa1[1]};
    const i32x4 FbOth = {(int)ob0[0], (int)ob0[1], (int)ob1[0], (int)ob1[1]};
    __builtin_amdgcn_s_setprio(1);
    P1[0]  = mfma_i8(WA[0][0], FaOwn, ZI);
    P1[1]  = mfma_i8(WA[1][0], FaOwn, ZI);
    P23[0] = mfma_i8(WB[0][0], FaOwn, ZI);
    P23[1] = mfma_i8(WB[1][0], FaOwn, ZI);
    P23[0] = mfma_i8(WA[0][0], FbOwn, P23[0]);
    P23[1] = mfma_i8(WA[1][0], FbOwn, P23[1]);
    P1[0]  = mfma_i8(WA[0][1], FaOth, P1[0]);
    P1[1]  = mfma_i8(WA[1][1], FaOth, P1[1]);
    P23[0] = mfma_i8(WB[0][1], FaOth, P23[0]);
    P23[1] = mfma_i8(WB[1][1], FaOth, P23[1]);
    P23[0] = mfma_i8(WA[0][1], FbOth, P23[0]);
    P23[1] = mfma_i8(WA[1][1], FbOth, P23[1]);
    __builtin_amdgcn_s_setprio(0);
  };

  // EPI role: consume P1/P23 + xv -> tanh -> 15-bit quant -> own frags + write.
  auto do_epi = [&](float xv) {
    unsigned napk[2], nbpk[2];
    #pragma unroll
    for (int mt = 0; mt < 2; ++mt) {
      float tp0, tp1, tp2, tp3;
      {
        const int X0 = (P1[mt][0] << 8) + P23[mt][0];
        const int X1 = (P1[mt][1] << 8) + P23[mt][1];
        const int X2 = (P1[mt][2] << 8) + P23[mt][2];
        const int X3 = (P1[mt][3] << 8) + P23[mt][3];
        const float v0 = __builtin_fmaf(kk2[mt][0], (float)X0,
                           __builtin_fmaf(wx2[mt][0], xv, bh2[mt][0]));
        const float v1 = __builtin_fmaf(kk2[mt][1], (float)X1,
                           __builtin_fmaf(wx2[mt][1], xv, bh2[mt][1]));
        const float v2 = __builtin_fmaf(kk2[mt][2], (float)X2,
                           __builtin_fmaf(wx2[mt][2], xv, bh2[mt][2]));
        const float v3 = __builtin_fmaf(kk2[mt][3], (float)X3,
                           __builtin_fmaf(wx2[mt][3], xv, bh2[mt][3]));
        const float e0 = __builtin_amdgcn_exp2f(v0);
        const float e1 = __builtin_amdgcn_exp2f(v1);
        const float e2 = __builtin_amdgcn_exp2f(v2);
        const float e3 = __builtin_amdgcn_exp2f(v3);
        const float r0 = __builtin_amdgcn_rcpf(e0 + 1.0f);
        const float r1 = __builtin_amdgcn_rcpf(e1 + 1.0f);
        const float r2 = __builtin_amdgcn_rcpf(e2 + 1.0f);
        const float r3 = __builtin_amdgcn_rcpf(e3 + 1.0f);
        tp0 = __builtin_fmaf(r0, TPN, TPP);
        tp1 = __builtin_fmaf(r1, TPN, TPP);
        tp2 = __builtin_fmaf(r2, TPN, TPP);
        tp3 = __builtin_fmaf(r3, TPN, TPP);
      }
      unsigned q01, q23, a01, a23, pa, pb;
      asm("v_cvt_pknorm_i16_f32 %0, %1, %2" : "=v"(q01) : "v"(tp0), "v"(tp1));
      asm("v_cvt_pknorm_i16_f32 %0, %1, %2" : "=v"(q23) : "v"(tp2), "v"(tp3));
      asm("v_pk_add_i16 %0, %1, %2" : "=v"(a01) : "v"(q01), "v"(c0080));
      asm("v_pk_add_i16 %0, %1, %2" : "=v"(a23) : "v"(q23), "v"(c0080));
      asm("v_perm_b32 %0, %1, %2, %3" : "=v"(pa) : "v"(a23), "v"(a01), "v"(selA));
      asm("v_perm_b32 %0, %1, %2, %3" : "=v"(pb) : "v"(q23), "v"(q01), "v"(selB));
      napk[mt] = pa; nbpk[mt] = pb;
    }
    ownA = u32x2{napk[0], napk[1]};
    ownB = u32x2{nbpk[0], nbpk[1]};
    hbuf[grp][sw][0][hw][lane] = ownA;    // 2 x ds_write_b64
    hbuf[grp][sw][1][hw][lane] = ownB;
  };

  for (int t4 = 0; t4 < RNN_T/4; ++t4) {
    f32x4 xn = xc;
    if (t4 + 1 < RNN_T/4) xn = *(const f32x4*)(px + 4*t4 + 4);
    #pragma unroll
    for (int qq = 0; qq < 4; ++qq) {
      const float xv = xc[qq];
      // interval 1: A waves MFMA(h_A(t)); B waves epi -> h_B(t+1)
      if (grp == 0) do_mfma(); else do_epi(xv);
      BAR();
      // interval 2: A waves epi -> h_A(t+1); B waves MFMA(h_B(t+1))
      if (grp == 0) do_epi(xv); else do_mfma();
      BAR();
    }
    xc = xn;
  }

  __syncthreads();

  // ---- projection: out[b][c] = w_ph[c,:] . h_last[:,b] + b_p[c] ----
  // h_A(T) in hbuf[0], h_B(T) in hbuf[1]; h = (256*a + b)/32512.
  {
    const int c   = tid >> 5;
    const int n32 = tid & 31;
    if (c < RNN_C) {
      const int tile = n32 >> 4;
      const int n    = n32 & 15;
      float sum = b_p[c];
      for (int k = 0; k < RNN_H; ++k) {
        const int s  = k >> 6;
        const int ko = k & 63;
        const int g2 = (ko >> 2) & 3;
        const int j  = (ko & 3) + 4*(ko >> 4);
        const int half = j >> 3, jj = j & 7;
        const signed char* pa = (const signed char*)&hbuf[tile][s][0][half][16*g2 + n];
        const signed char* pb = (const signed char*)&hbuf[tile][s][1][half][16*g2 + n];
        const int qv = 256*(int)pa[jj] + (int)pb[jj];
        sum = __builtin_fmaf(w_ph[c*RNN_H + k], qv * (1.0f/QSW), sum);
      }
      out[(size_t)(n0 + n32)*RNN_C + c] = sum;
    }
  }
}

extern "C" void kernel_launch(void* const* d_in, const int* in_sizes, int n_in,
                              void* d_out, int out_size, void* d_ws, size_t ws_size,
                              hipStream_t stream) {
  (void)in_sizes; (void)n_in; (void)out_size; (void)d_ws; (void)ws_size;
  const float* x    = (const float*)d_in[0];
  const float* w_hx = (const float*)d_in[1];
  const float* w_hh = (const float*)d_in[2];
  const float* b_h  = (const float*)d_in[3];
  const float* w_ph = (const float*)d_in[4];
  const float* b_p  = (const float*)d_in[5];
  float* out = (float*)d_out;
  rnn_fused<<<dim3(RNN_B/BLK_N), dim3(512), 0, stream>>>(x, w_hx, w_hh, b_h, w_ph, b_p, out);
}

// Round 15
// 1021.151 us; speedup vs baseline: 1.5085x; 1.5085x over previous
//
#include <hip/hip_runtime.h>

typedef int      i32x4 __attribute__((ext_vector_type(4)));
typedef float    f32x4 __attribute__((ext_vector_type(4)));
typedef unsigned u32x2 __attribute__((ext_vector_type(2)));

#define RNN_H 128
#define RNN_T 2048
#define RNN_B 8192
#define RNN_C 10
#define BLK_N 16
#define QSW 32512.0f            // 127*256: fixed-point scale for W and h
#define K2E 2.885390081777927f  // 2*log2(e), folded into kk/wx/bh

// LDS-only barrier: drain ds ops, never vmcnt (x prefetch stays in flight).
#define BAR() asm volatile("s_waitcnt lgkmcnt(0)\n\ts_barrier" ::: "memory")
#define MEMPIN() asm volatile("" ::: "memory")

__device__ __forceinline__ i32x4 mfma_i8(i32x4 a, i32x4 b, i32x4 c) {
  return __builtin_amdgcn_mfma_i32_16x16x64_i8(a, b, c, 0, 0, 0);
}

// k-bijection for 16x16x64 i8 frags (byte p of the 4-dword operand, lane
// group g = lane>>4): k = 64*slot + 4g + (p&3) + 16*jg(p>>2). Per-wave jg
// permutation puts the own-half j-groups at frag dwords 0,1 (A-fill permuted
// identically, so sum over k is unchanged) -> register recycle, no muxes.
// h = q/32512, q = 256a + b; W row-scaled 15-bit -> (wa, wb) int8 pairs.
// X = 256*P1 + P23, P1 = S wa*a, P23 = S(wa*b + wb*a) (wb*b dropped ~2e-5).
// LDS: [buf][slot][part a/b][half][lane] u32x2 -> 6 x ds_read_b64 +
// 2 x ds_write_b64 per wave-step, 0 bank conflicts (r11-verified).

__global__ __launch_bounds__(256, 2)
void rnn_fused(const float* __restrict__ x, const float* __restrict__ w_hx,
               const float* __restrict__ w_hh, const float* __restrict__ b_h,
               const float* __restrict__ w_ph, const float* __restrict__ b_p,
               float* __restrict__ out)
{
  // h double-buffered: [buf][slot(2)][part a/b][half(2)][lane(64)] x 8B = 8 KiB
  __shared__ u32x2 hbuf[2][2][2][2][64];
  __shared__ float rs[128];   // per-row W scales for C/D-lane redistribution

  const int tid  = threadIdx.x;
  const int lane = tid & 63;
  const int wv   = tid >> 6;       // 0..3: rows [32wv, 32wv+32)
  const int g    = lane >> 4;
  const int l15  = lane & 15;
  const int n0   = blockIdx.x * BLK_N;
  const int sw = wv >> 1, hw = wv & 1, so = sw ^ 1;

  { // zero h(0) = buffer 0 (512 u32x2 entries)
    u32x2 z = {0u, 0u};
    u32x2* p = &hbuf[0][0][0][0][0];
    p[tid] = z; p[tid + 256] = z;
  }

  // ---- W quantization: per-row 15-bit fixed point, split to int8 (wa, wb).
  // li = 0: own slot with per-wave jg permutation; li = 1: other slot natural.
  i32x4 WA[2][2], WB[2][2];
  float rm[2];
  #pragma unroll
  for (int mt = 0; mt < 2; ++mt) {
    const float* wrow = w_hh + (size_t)(wv*32 + mt*16 + l15)*RNN_H + 4*g;
    float vals[2][4][4];
    float mx = 0.0f;
    #pragma unroll
    for (int li = 0; li < 2; ++li) {
      const int s = li ? so : sw;
      #pragma unroll
      for (int d = 0; d < 4; ++d) {
        const int jg = li ? d : ((d < 2) ? (2*hw + d) : (2*(hw^1) + (d-2)));
        f32x4 v = *(const f32x4*)(wrow + s*64 + jg*16);
        #pragma unroll
        for (int r = 0; r < 4; ++r) { vals[li][d][r] = v[r]; mx = fmaxf(mx, fabsf(v[r])); }
      }
    }
    mx = fmaxf(mx, __shfl_xor(mx, 16));   // combine the 4 g-lanes of this row
    mx = fmaxf(mx, __shfl_xor(mx, 32));
    const float inv = (mx > 0.0f) ? (QSW / mx) : 0.0f;
    rm[mt] = mx * (1.0f / QSW);
    #pragma unroll
    for (int li = 0; li < 2; ++li)
      #pragma unroll
      for (int d = 0; d < 4; ++d) {
        unsigned pa = 0, pb = 0;
        #pragma unroll
        for (int r = 0; r < 4; ++r) {
          const int Wq  = (int)rintf(vals[li][d][r] * inv);  // |Wq| <= 32512
          const int wa  = (Wq + 128) >> 8;                   // [-127, 127]
          const int wbv = Wq - (wa << 8);                    // [-128, 127]
          pa |= ((unsigned)(wa  & 255)) << (8*r);
          pb |= ((unsigned)(wbv & 255)) << (8*r);
        }
        WA[mt][li][d] = (int)pa;
        WB[mt][li][d] = (int)pb;
      }
  }

  if (g == 0) {                       // publish row scales (rows 32wv+16mt+l15)
    rs[wv*32 +  0 + l15] = rm[0];
    rs[wv*32 + 16 + l15] = rm[1];
  }
  __syncthreads();

  // per-C/D-reg constants (K2E folded): m = 32wv + 16mt + 4g + r
  f32x4 kk2[2], wx2[2], bh2[2];
  #pragma unroll
  for (int mt = 0; mt < 2; ++mt)
    #pragma unroll
    for (int r = 0; r < 4; ++r) {
      const int m = wv*32 + mt*16 + 4*g + r;
      kk2[mt][r] = rs[m] * (K2E / 127.0f);
      wx2[mt][r] = w_hx[m] * K2E;
      bh2[mt][r] = b_h[m] * K2E;
    }

  const float* px = x + (size_t)(n0 + l15) * RNN_T;
  f32x4 xc = *(const f32x4*)px;

  const i32x4 ZI = {0,0,0,0};
  u32x2 ownA = {0u,0u}, ownB = {0u,0u};   // own half frags (h(0) = 0)

  // epilogue constants (VGPR-resident; v_perm/v_pk_add take no literals)
  const unsigned c0080 = 0x00800080u;   // +128 per i16 (a-byte rounding)
  const unsigned selA  = 0x07050301u;   // a-bytes: bytes 1,3 of each i16 pair
  const unsigned selB  = 0x06040200u;   // b-bytes: bytes 0,2
  const float TPP = 32512.0f / 32767.0f;  // pknorm prescale -> q = rint(t*32512)
  const float TPN = -2.0f * TPP;

  __syncthreads();

  // anti-phase stagger, contiguous-pairing hypothesis: co-resident pair on a
  // CU = (2b, 2b+1). Odd blocks delay ~540 cy (half a step) once, so their
  // MFMA phase overlaps the even block's epi phase. Anti-phase should be
  // self-stabilizing: a block in its MFMA phase sees an uncontended matrix
  // pipe only while its neighbor runs epi, and vice versa. (r13 tested the
  // strided guess (b, b+256) -- null, but confounded by a b128 regression.)
  if (blockIdx.x & 1) {
    float acc = (float)lane;
    #pragma unroll 1
    for (int i = 0; i < 135; ++i) acc = __builtin_fmaf(acc, 0.9999f, 1.0f);
    if (acc == 12345.678f) rs[0] = acc;   // unreachable; keeps loop alive
  }

  for (int t4 = 0; t4 < RNN_T/4; ++t4) {
    f32x4 xn = xc;
    if (t4 + 1 < RNN_T/4) xn = *(const f32x4*)(px + 4*t4 + 4);
    #pragma unroll
    for (int qq = 0; qq < 4; ++qq) {
      const int rb = qq & 1, wb2 = rb ^ 1;
      const float xv = xc[qq];

      // 6 x ds_read_b64 (conflict-free): partner half first (feeds MFMA #1)
      const u32x2 poA = hbuf[rb][sw][0][hw^1][lane];
      const u32x2 poB = hbuf[rb][sw][1][hw^1][lane];
      const u32x2 oa0 = hbuf[rb][so][0][0][lane];
      const u32x2 oa1 = hbuf[rb][so][0][1][lane];
      const u32x2 ob0 = hbuf[rb][so][1][0][lane];
      const u32x2 ob1 = hbuf[rb][so][1][1][lane];
      MEMPIN();

      // static fragment assembly (no muxes; own half always dwords 0,1)
      const i32x4 FaOwn = {(int)ownA[0], (int)ownA[1], (int)poA[0], (int)poA[1]};
      const i32x4 FbOwn = {(int)ownB[0], (int)ownB[1], (int)poB[0], (int)poB[1]};
      const i32x4 FaOth = {(int)oa0[0], (int)oa0[1], (int)oa1[0], (int)oa1[1]};
      const i32x4 FbOth = {(int)ob0[0], (int)ob0[1], (int)ob1[0], (int)ob1[1]};

      // 12 i8 MFMAs, 4 chains (P1 x2 depth 2, P23 x2 depth 4)
      i32x4 P1[2], P23[2];
      __builtin_amdgcn_s_setprio(1);
      P1[0]  = mfma_i8(WA[0][0], FaOwn, ZI);
      P1[1]  = mfma_i8(WA[1][0], FaOwn, ZI);
      P23[0] = mfma_i8(WB[0][0], FaOwn, ZI);
      P23[1] = mfma_i8(WB[1][0], FaOwn, ZI);
      P23[0] = mfma_i8(WA[0][0], FbOwn, P23[0]);
      P23[1] = mfma_i8(WA[1][0], FbOwn, P23[1]);
      P1[0]  = mfma_i8(WA[0][1], FaOth, P1[0]);
      P1[1]  = mfma_i8(WA[1][1], FaOth, P1[1]);
      P23[0] = mfma_i8(WB[0][1], FaOth, P23[0]);
      P23[1] = mfma_i8(WB[1][1], FaOth, P23[1]);
      P23[0] = mfma_i8(WA[0][1], FbOth, P23[0]);
      P23[1] = mfma_i8(WA[1][1], FbOth, P23[1]);
      __builtin_amdgcn_s_setprio(0);

      // epilogue: X -> tanh (exp2+rcp) -> pknorm i16 -> byte split via perm
      unsigned napk[2], nbpk[2];
      #pragma unroll
      for (int mt = 0; mt < 2; ++mt) {
        float tp0, tp1, tp2, tp3;
        {
          const int X0 = (P1[mt][0] << 8) + P23[mt][0];
          const int X1 = (P1[mt][1] << 8) + P23[mt][1];
          const int X2 = (P1[mt][2] << 8) + P23[mt][2];
          const int X3 = (P1[mt][3] << 8) + P23[mt][3];
          const float v0 = __builtin_fmaf(kk2[mt][0], (float)X0,
                             __builtin_fmaf(wx2[mt][0], xv, bh2[mt][0]));
          const float v1 = __builtin_fmaf(kk2[mt][1], (float)X1,
                             __builtin_fmaf(wx2[mt][1], xv, bh2[mt][1]));
          const float v2 = __builtin_fmaf(kk2[mt][2], (float)X2,
                             __builtin_fmaf(wx2[mt][2], xv, bh2[mt][2]));
          const float v3 = __builtin_fmaf(kk2[mt][3], (float)X3,
                             __builtin_fmaf(wx2[mt][3], xv, bh2[mt][3]));
          const float e0 = __builtin_amdgcn_exp2f(v0);
          const float e1 = __builtin_amdgcn_exp2f(v1);
          const float e2 = __builtin_amdgcn_exp2f(v2);
          const float e3 = __builtin_amdgcn_exp2f(v3);
          const float r0 = __builtin_amdgcn_rcpf(e0 + 1.0f);
          const float r1 = __builtin_amdgcn_rcpf(e1 + 1.0f);
          const float r2 = __builtin_amdgcn_rcpf(e2 + 1.0f);
          const float r3 = __builtin_amdgcn_rcpf(e3 + 1.0f);
          tp0 = __builtin_fmaf(r0, TPN, TPP);
          tp1 = __builtin_fmaf(r1, TPN, TPP);
          tp2 = __builtin_fmaf(r2, TPN, TPP);
          tp3 = __builtin_fmaf(r3, TPN, TPP);
        }
        unsigned q01, q23, a01, a23, pa, pb;
        asm("v_cvt_pknorm_i16_f32 %0, %1, %2" : "=v"(q01) : "v"(tp0), "v"(tp1));
        asm("v_cvt_pknorm_i16_f32 %0, %1, %2" : "=v"(q23) : "v"(tp2), "v"(tp3));
        asm("v_pk_add_i16 %0, %1, %2" : "=v"(a01) : "v"(q01), "v"(c0080));
        asm("v_pk_add_i16 %0, %1, %2" : "=v"(a23) : "v"(q23), "v"(c0080));
        asm("v_perm_b32 %0, %1, %2, %3" : "=v"(pa) : "v"(a23), "v"(a01), "v"(selA));
        asm("v_perm_b32 %0, %1, %2, %3" : "=v"(pb) : "v"(q23), "v"(q01), "v"(selB));
        napk[mt] = pa; nbpk[mt] = pb;
      }
      ownA = u32x2{napk[0], napk[1]};
      ownB = u32x2{nbpk[0], nbpk[1]};

      // publish own half (2 x ds_write_b64)
      hbuf[wb2][sw][0][hw][lane] = ownA;
      hbuf[wb2][sw][1][hw][lane] = ownB;
      BAR();
    }
    xc = xn;
  }

  __syncthreads();

  // ---- projection: out[b][c] = w_ph[c,:] . h_last[:,b] + b_p[c] ----
  // t=2047 wrote buffer 0; h = (256*a + b) / 32512.
  {
    const int c = tid >> 4;
    const int n = tid & 15;
    if (c < RNN_C) {
      float sum = b_p[c];
      for (int k = 0; k < RNN_H; ++k) {
        const int s  = k >> 6;
        const int ko = k & 63;
        const int g2 = (ko >> 2) & 3;
        const int j  = (ko & 3) + 4*(ko >> 4);
        const int half = j >> 3, jj = j & 7;
        const signed char* pa = (const signed char*)&hbuf[0][s][0][half][16*g2 + n];
        const signed char* pb = (const signed char*)&hbuf[0][s][1][half][16*g2 + n];
        const int qv = 256*(int)pa[jj] + (int)pb[jj];
        sum = __builtin_fmaf(w_ph[c*RNN_H + k], qv * (1.0f/QSW), sum);
      }
      out[(size_t)(n0 + n)*RNN_C + c] = sum;
    }
  }
}

extern "C" void kernel_launch(void* const* d_in, const int* in_sizes, int n_in,
                              void* d_out, int out_size, void* d_ws, size_t ws_size,
                              hipStream_t stream) {
  (void)in_sizes; (void)n_in; (void)out_size; (void)d_ws; (void)ws_size;
  const float* x    = (const float*)d_in[0];
  const float* w_hx = (const float*)d_in[1];
  const float* w_hh = (const float*)d_in[2];
  const float* b_h  = (const float*)d_in[3];
  const float* w_ph = (const float*)d_in[4];
  const float* b_p  = (const float*)d_in[5];
  float* out = (float*)d_out;
  rnn_fused<<<dim3(RNN_B/BLK_N), dim3(256), 0, stream>>>(x, w_hx, w_hh, b_h, w_ph, b_p, out);
}